// Round 2
// baseline (2290.875 us; speedup 1.0000x reference)
//
#include <hip/hip_runtime.h>

typedef float f32x4 __attribute__((ext_vector_type(4)));

constexpr int C_ = 128;
constexpr int N_ = 4096;
constexpr int M_ = 512;
constexpr int NL = 6;

#define NEG_INF (-__builtin_huge_valf())

// ---------------------------------------------------------------------------
// Pool (flash over n): S = Wp@xs -> softmax_n -> h[m][c] += P@xs^T
// grid (16 = 4 mtiles * 4 nsegs, 32 b), 256 thr. thread (ty=t>>4, tx=t&15).
// S-phase: m = ty+16i (8), n = tx*4..+3. apply: m = ty+16i, c = tx+16j (8).
// Writes unnormalized h_part[seg][b][m][c] + per-row (M,L) for combine.
// ---------------------------------------------------------------------------
__global__ __launch_bounds__(256) void k_pool(const float* __restrict__ xs,
                                              const float* __restrict__ Wp,
                                              float* __restrict__ h_part,
                                              float* __restrict__ ml) {
  __shared__ float xs_s[128 * 68];
  __shared__ float P_s[128 * 68];
  const int bx = blockIdx.x;
  const int b = blockIdx.y;
  const int mt = bx >> 2, seg = bx & 3;
  const int m0 = mt * 128;
  const int t = threadIdx.x, ty = t >> 4, tx = t & 15;
  const float* xsb = xs + (size_t)b * C_ * N_;

  float Mrow[8], Lrow[8], hacc[8][8];
#pragma unroll
  for (int i = 0; i < 8; ++i) {
    Mrow[i] = NEG_INF;
    Lrow[i] = 0.f;
#pragma unroll
    for (int j = 0; j < 8; ++j) hacc[i][j] = 0.f;
  }

  for (int ch = 0; ch < 16; ++ch) {
    const int n0 = seg * 1024 + ch * 64;
    __syncthreads();
#pragma unroll
    for (int ii = 0; ii < 8; ++ii) {
      int f = ii * 1024 + t * 4;
      int c = f >> 6, n = f & 63;
      *(f32x4*)&xs_s[c * 68 + n] = *(const f32x4*)&xsb[(size_t)c * N_ + n0 + n];
    }
    __syncthreads();

    // ---- S = Wp @ xs ----
    f32x4 S[8];
#pragma unroll
    for (int i = 0; i < 8; ++i) S[i] = f32x4{0.f, 0.f, 0.f, 0.f};
    for (int c4 = 0; c4 < 128; c4 += 4) {
      f32x4 a4[8];
#pragma unroll
      for (int i = 0; i < 8; ++i)
        a4[i] = *(const f32x4*)&Wp[(size_t)(m0 + ty + 16 * i) * 128 + c4];
#pragma unroll
      for (int cc = 0; cc < 4; ++cc) {
        f32x4 b4 = *(f32x4*)&xs_s[(c4 + cc) * 68 + tx * 4];
#pragma unroll
        for (int i = 0; i < 8; ++i) S[i] += a4[i][cc] * b4;
      }
    }

    // ---- online softmax per m-row ----
#pragma unroll
    for (int i = 0; i < 8; ++i) {
      float mx = fmaxf(fmaxf(S[i][0], S[i][1]), fmaxf(S[i][2], S[i][3]));
#pragma unroll
      for (int off = 1; off < 16; off <<= 1) mx = fmaxf(mx, __shfl_xor(mx, off));
      float mn = fmaxf(Mrow[i], mx);
      float al = __expf(Mrow[i] - mn);
      Mrow[i] = mn;
      f32x4 p;
      float s = 0.f;
#pragma unroll
      for (int nn = 0; nn < 4; ++nn) {
        p[nn] = __expf(S[i][nn] - mn);
        s += p[nn];
      }
#pragma unroll
      for (int off = 1; off < 16; off <<= 1) s += __shfl_xor(s, off);
      Lrow[i] = Lrow[i] * al + s;
      *(f32x4*)&P_s[(ty + 16 * i) * 68 + tx * 4] = p;
#pragma unroll
      for (int j = 0; j < 8; ++j) hacc[i][j] *= al;
    }
    __syncthreads();

    // ---- apply: h[m][c] += sum_n P[m][n] * xs[c][n] ----
    for (int n4 = 0; n4 < 64; n4 += 4) {
      f32x4 p4[8], x4[8];
#pragma unroll
      for (int i = 0; i < 8; ++i) p4[i] = *(f32x4*)&P_s[(ty + 16 * i) * 68 + n4];
#pragma unroll
      for (int j = 0; j < 8; ++j) x4[j] = *(f32x4*)&xs_s[(tx + 16 * j) * 68 + n4];
#pragma unroll
      for (int i = 0; i < 8; ++i)
#pragma unroll
        for (int j = 0; j < 8; ++j) {
          hacc[i][j] += p4[i][0] * x4[j][0];
          hacc[i][j] += p4[i][1] * x4[j][1];
          hacc[i][j] += p4[i][2] * x4[j][2];
          hacc[i][j] += p4[i][3] * x4[j][3];
        }
    }
  }

  const size_t sb = (size_t)seg * 32 + b;
#pragma unroll
  for (int i = 0; i < 8; ++i) {
    const int m = m0 + ty + 16 * i;
    if (tx == 0) {
      ml[(sb * 512 + m) * 2] = Mrow[i];
      ml[(sb * 512 + m) * 2 + 1] = Lrow[i];
    }
#pragma unroll
    for (int j = 0; j < 8; ++j)
      h_part[(sb * 512 + m) * 128 + tx + 16 * j] = hacc[i][j];
  }
}

// ---------------------------------------------------------------------------
// Combine 4 n-segments: h[m][b*128+c] = sum_s w_s*h_s / sum_s w_s*L_s
// ---------------------------------------------------------------------------
__global__ __launch_bounds__(128) void k_combine(const float* __restrict__ h_part,
                                                 const float* __restrict__ ml,
                                                 float* __restrict__ hbuf) {
  const int mb = blockIdx.x;  // m*32 + b
  const int m = mb >> 5, b = mb & 31;
  const int c = threadIdx.x;
  float Ms[4], M = NEG_INF;
#pragma unroll
  for (int s = 0; s < 4; ++s) {
    Ms[s] = ml[(((size_t)s * 32 + b) * 512 + m) * 2];
    M = fmaxf(M, Ms[s]);
  }
  float w[4], L = 0.f;
#pragma unroll
  for (int s = 0; s < 4; ++s) {
    w[s] = __expf(Ms[s] - M);
    L += w[s] * ml[(((size_t)s * 32 + b) * 512 + m) * 2 + 1];
  }
  float acc = 0.f;
#pragma unroll
  for (int s = 0; s < 4; ++s)
    acc += w[s] * h_part[(((size_t)s * 32 + b) * 512 + m) * 128 + c];
  hbuf[(size_t)m * 4096 + b * 128 + c] = acc / L;
}

// ---------------------------------------------------------------------------
// Layer GEMM: y[o][bc] = sum_m Wf[l][o][m] * h[m][bc]  (+ per-o sum/sumsq)
// grid (8 o-tiles of 64, 32 bc-tiles of 128). thread (ty=t>>5, tx=t&31):
// o = o0+ty+8i (8 rows), bc = bc0+tx*4 (4 cols).
// ---------------------------------------------------------------------------
__global__ __launch_bounds__(256) void k_layerA(const float* __restrict__ hbuf,
                                                const float* __restrict__ Wf, int l,
                                                float* __restrict__ ybuf,
                                                float* __restrict__ stats) {
  __shared__ float B_s[32 * 132];
  const int o0 = blockIdx.x * 64;
  const int bc0 = blockIdx.y * 128;
  const int t = threadIdx.x, ty = t >> 5, tx = t & 31;
  const float* Wl = Wf + (size_t)l * M_ * M_;

  f32x4 acc[8];
#pragma unroll
  for (int i = 0; i < 8; ++i) acc[i] = f32x4{0.f, 0.f, 0.f, 0.f};

  for (int k0 = 0; k0 < 512; k0 += 32) {
    __syncthreads();
#pragma unroll
    for (int ii = 0; ii < 4; ++ii) {
      int f = ii * 1024 + t * 4;
      int mm = f >> 7, cc = f & 127;
      *(f32x4*)&B_s[mm * 132 + cc] =
          *(const f32x4*)&hbuf[(size_t)(k0 + mm) * 4096 + bc0 + cc];
    }
    __syncthreads();
#pragma unroll 2
    for (int k4 = 0; k4 < 32; k4 += 4) {
      f32x4 a4[8];
#pragma unroll
      for (int i = 0; i < 8; ++i)
        a4[i] = *(const f32x4*)&Wl[(size_t)(o0 + ty + 8 * i) * 512 + k0 + k4];
#pragma unroll
      for (int kk = 0; kk < 4; ++kk) {
        f32x4 b4 = *(f32x4*)&B_s[(k4 + kk) * 132 + tx * 4];
#pragma unroll
        for (int i = 0; i < 8; ++i) acc[i] += a4[i][kk] * b4;
      }
    }
  }

#pragma unroll
  for (int i = 0; i < 8; ++i) {
    const int o = o0 + ty + 8 * i;
    *(f32x4*)&ybuf[(size_t)o * 4096 + bc0 + tx * 4] = acc[i];
    float s = acc[i][0] + acc[i][1] + acc[i][2] + acc[i][3];
    float s2 = acc[i][0] * acc[i][0] + acc[i][1] * acc[i][1] +
               acc[i][2] * acc[i][2] + acc[i][3] * acc[i][3];
#pragma unroll
    for (int off = 1; off < 32; off <<= 1) {
      s += __shfl_xor(s, off);
      s2 += __shfl_xor(s2, off);
    }
    if (tx == 0) {
      atomicAdd(&stats[l * 1024 + o], s);
      atomicAdd(&stats[l * 1024 + 512 + o], s2);
    }
  }
}

// ---------------------------------------------------------------------------
// BN + residual + relu elementwise over [o][bc]
// ---------------------------------------------------------------------------
__global__ __launch_bounds__(256) void k_layerB(const float* __restrict__ ybuf,
                                                float* __restrict__ hbuf,
                                                const float* __restrict__ stats,
                                                const float* __restrict__ gamma,
                                                const float* __restrict__ beta, int l) {
  const size_t i4 = ((size_t)blockIdx.x * 256 + threadIdx.x) * 4;
  const int o = (int)(i4 >> 12);
  f32x4 y = *(const f32x4*)&ybuf[i4];
  f32x4 h = *(const f32x4*)&hbuf[i4];
  const float mu = stats[l * 1024 + o] * (1.f / 4096.f);
  const float var = stats[l * 1024 + 512 + o] * (1.f / 4096.f) - mu * mu;
  const float rs = rsqrtf(var + 1e-5f);
  const float g = gamma[l * 512 + o];
  const float bt = beta[l * 512 + o];
  f32x4 r;
#pragma unroll
  for (int jj = 0; jj < 4; ++jj)
    r[jj] = fmaxf((y[jj] - mu) * rs * g + bt + h[jj], 0.f);
  *(f32x4*)&hbuf[i4] = r;
}

// ---------------------------------------------------------------------------
// Unpool (flash over m): ul = Wun@xs + b -> softmax_m -> out[c][n] = x1@S / L
// grid (32 n-tiles of 128, 32 b). thread (ty=t>>4, tx=t&15).
// logits: m = mc0+tx*4+i (4), n = n0+ty*8+j (8, contiguous).
// apply:  c = ty+16i (8), n = n0+tx+16j (8).
// ---------------------------------------------------------------------------
__global__ __launch_bounds__(256) void k_unpool(const float* __restrict__ xs,
                                                const float* __restrict__ Wun,
                                                const float* __restrict__ bun,
                                                const float* __restrict__ hbuf,
                                                float* __restrict__ out) {
  __shared__ float P_s[64 * 133];
  __shared__ float alpha_s[128];
  __shared__ float L_s[128];
  const int n0 = blockIdx.x * 128;
  const int b = blockIdx.y;
  const int t = threadIdx.x, ty = t >> 4, tx = t & 15;
  const float* xsb = xs + (size_t)b * C_ * N_;

  float acc[8][8];
#pragma unroll
  for (int i = 0; i < 8; ++i)
#pragma unroll
    for (int j = 0; j < 8; ++j) acc[i][j] = 0.f;
  float Mn[8], Ln[8];
#pragma unroll
  for (int j = 0; j < 8; ++j) {
    Mn[j] = NEG_INF;
    Ln[j] = 0.f;
  }

  for (int ch = 0; ch < 8; ++ch) {
    const int mc0 = ch * 64;
    // ---- logits ----
    f32x4 ulv[4][2];
#pragma unroll
    for (int i = 0; i < 4; ++i) {
      const float bi = bun[mc0 + tx * 4 + i];
      ulv[i][0] = f32x4{bi, bi, bi, bi};
      ulv[i][1] = f32x4{bi, bi, bi, bi};
    }
    for (int c4 = 0; c4 < 128; c4 += 4) {
      f32x4 a4[4];
#pragma unroll
      for (int i = 0; i < 4; ++i)
        a4[i] = *(const f32x4*)&Wun[(size_t)(mc0 + tx * 4 + i) * 128 + c4];
#pragma unroll
      for (int cc = 0; cc < 4; ++cc) {
        const float* xp = &xsb[(size_t)(c4 + cc) * N_ + n0 + ty * 8];
        f32x4 xv0 = *(const f32x4*)xp;
        f32x4 xv1 = *(const f32x4*)(xp + 4);
#pragma unroll
        for (int i = 0; i < 4; ++i) {
          ulv[i][0] += a4[i][cc] * xv0;
          ulv[i][1] += a4[i][cc] * xv1;
        }
      }
    }
    // ---- online softmax over m (reduce over i and tx) ----
    float pv[4][8];
#pragma unroll
    for (int j = 0; j < 8; ++j) {
      float u0 = ulv[0][j >> 2][j & 3], u1 = ulv[1][j >> 2][j & 3];
      float u2 = ulv[2][j >> 2][j & 3], u3 = ulv[3][j >> 2][j & 3];
      float mx = fmaxf(fmaxf(u0, u1), fmaxf(u2, u3));
#pragma unroll
      for (int off = 1; off < 16; off <<= 1) mx = fmaxf(mx, __shfl_xor(mx, off));
      float mn = fmaxf(Mn[j], mx);
      float al = __expf(Mn[j] - mn);
      Mn[j] = mn;
      pv[0][j] = __expf(u0 - mn);
      pv[1][j] = __expf(u1 - mn);
      pv[2][j] = __expf(u2 - mn);
      pv[3][j] = __expf(u3 - mn);
      float s = pv[0][j] + pv[1][j] + pv[2][j] + pv[3][j];
#pragma unroll
      for (int off = 1; off < 16; off <<= 1) s += __shfl_xor(s, off);
      Ln[j] = Ln[j] * al + s;
      if (tx == 0) {
        alpha_s[ty * 8 + j] = al;
        L_s[ty * 8 + j] = Ln[j];
      }
    }
#pragma unroll
    for (int i = 0; i < 4; ++i)
#pragma unroll
      for (int j = 0; j < 8; ++j)
        P_s[(tx * 4 + i) * 133 + ty * 8 + j] = pv[i][j];
    __syncthreads();

    // ---- rescale + apply ----
    float al[8];
#pragma unroll
    for (int j = 0; j < 8; ++j) al[j] = alpha_s[tx + 16 * j];
#pragma unroll
    for (int i = 0; i < 8; ++i)
#pragma unroll
      for (int j = 0; j < 8; ++j) acc[i][j] *= al[j];
    for (int m = 0; m < 64; ++m) {
      float hv[8], pw[8];
#pragma unroll
      for (int i = 0; i < 8; ++i)
        hv[i] = hbuf[(size_t)(mc0 + m) * 4096 + b * 128 + ty + 16 * i];
#pragma unroll
      for (int j = 0; j < 8; ++j) pw[j] = P_s[m * 133 + tx + 16 * j];
#pragma unroll
      for (int i = 0; i < 8; ++i)
#pragma unroll
        for (int j = 0; j < 8; ++j) acc[i][j] += hv[i] * pw[j];
    }
    __syncthreads();
  }

  float inv[8];
#pragma unroll
  for (int j = 0; j < 8; ++j) inv[j] = 1.f / L_s[tx + 16 * j];
#pragma unroll
  for (int i = 0; i < 8; ++i)
#pragma unroll
    for (int j = 0; j < 8; ++j)
      out[((size_t)b * 128 + ty + 16 * i) * (size_t)N_ + n0 + tx + 16 * j] =
          acc[i][j] * inv[j];
}

// ---------------------------------------------------------------------------
extern "C" void kernel_launch(void* const* d_in, const int* in_sizes, int n_in,
                              void* d_out, int out_size, void* d_ws, size_t ws_size,
                              hipStream_t stream) {
  const float* x = (const float*)d_in[0];
  const float* W_pool = (const float*)d_in[1];
  const float* Wf = (const float*)d_in[2];
  const float* gamma = (const float*)d_in[3];
  const float* beta = (const float*)d_in[4];
  const float* W_unpool = (const float*)d_in[5];
  const float* b_unpool = (const float*)d_in[6];
  float* out = (float*)d_out;

  char* ws = (char*)d_ws;
  float* h_part = (float*)ws; ws += (size_t)4 * 32 * 512 * 128 * 4;  // 33.6 MB
  float* ml = (float*)ws;     ws += (size_t)4 * 32 * 512 * 2 * 4;    // 0.5 MB
  float* hbuf = (float*)ws;   ws += (size_t)512 * 4096 * 4;          // 8.4 MB
  float* ybuf = (float*)ws;   ws += (size_t)512 * 4096 * 4;          // 8.4 MB
  float* stats = (float*)ws;  ws += NL * 1024 * 4;

  hipMemsetAsync(stats, 0, NL * 1024 * 4, stream);
  k_pool<<<dim3(16, 32), 256, 0, stream>>>(x, W_pool, h_part, ml);
  k_combine<<<dim3(16384), 128, 0, stream>>>(h_part, ml, hbuf);
  for (int l = 0; l < NL; ++l) {
    k_layerA<<<dim3(8, 32), 256, 0, stream>>>(hbuf, Wf, l, ybuf, stats);
    k_layerB<<<dim3(2048), 256, 0, stream>>>(ybuf, hbuf, stats, gamma, beta, l);
  }
  k_unpool<<<dim3(32, 32), 256, 0, stream>>>(x, W_unpool, b_unpool, hbuf, out);
}

// Round 3
// 1680.139 us; speedup vs baseline: 1.3635x; 1.3635x over previous
//
#include <hip/hip_runtime.h>
#include <hip/hip_bf16.h>

typedef float f32x4 __attribute__((ext_vector_type(4)));
typedef __bf16 bf16_t;
typedef __bf16 bf16x4 __attribute__((ext_vector_type(4)));
typedef __bf16 bf16x8 __attribute__((ext_vector_type(8)));

#define MFMA16(a, b, c) __builtin_amdgcn_mfma_f32_16x16x32_bf16(a, b, c, 0, 0, 0)

constexpr int C_ = 128;
constexpr int N_ = 4096;
constexpr int M_ = 512;
constexpr int NL = 6;

#define NEG_INF (-__builtin_huge_valf())

// ---------------------------------------------------------------------------
// Pool (flash over n) — unchanged from round 2.
// ---------------------------------------------------------------------------
__global__ __launch_bounds__(256) void k_pool(const float* __restrict__ xs,
                                              const float* __restrict__ Wp,
                                              float* __restrict__ h_part,
                                              float* __restrict__ ml) {
  __shared__ float xs_s[128 * 68];
  __shared__ float P_s[128 * 68];
  const int bx = blockIdx.x;
  const int b = blockIdx.y;
  const int mt = bx >> 2, seg = bx & 3;
  const int m0 = mt * 128;
  const int t = threadIdx.x, ty = t >> 4, tx = t & 15;
  const float* xsb = xs + (size_t)b * C_ * N_;

  float Mrow[8], Lrow[8], hacc[8][8];
#pragma unroll
  for (int i = 0; i < 8; ++i) {
    Mrow[i] = NEG_INF;
    Lrow[i] = 0.f;
#pragma unroll
    for (int j = 0; j < 8; ++j) hacc[i][j] = 0.f;
  }

  for (int ch = 0; ch < 16; ++ch) {
    const int n0 = seg * 1024 + ch * 64;
    __syncthreads();
#pragma unroll
    for (int ii = 0; ii < 8; ++ii) {
      int f = ii * 1024 + t * 4;
      int c = f >> 6, n = f & 63;
      *(f32x4*)&xs_s[c * 68 + n] = *(const f32x4*)&xsb[(size_t)c * N_ + n0 + n];
    }
    __syncthreads();

    f32x4 S[8];
#pragma unroll
    for (int i = 0; i < 8; ++i) S[i] = f32x4{0.f, 0.f, 0.f, 0.f};
    for (int c4 = 0; c4 < 128; c4 += 4) {
      f32x4 a4[8];
#pragma unroll
      for (int i = 0; i < 8; ++i)
        a4[i] = *(const f32x4*)&Wp[(size_t)(m0 + ty + 16 * i) * 128 + c4];
#pragma unroll
      for (int cc = 0; cc < 4; ++cc) {
        f32x4 b4 = *(f32x4*)&xs_s[(c4 + cc) * 68 + tx * 4];
#pragma unroll
        for (int i = 0; i < 8; ++i) S[i] += a4[i][cc] * b4;
      }
    }

#pragma unroll
    for (int i = 0; i < 8; ++i) {
      float mx = fmaxf(fmaxf(S[i][0], S[i][1]), fmaxf(S[i][2], S[i][3]));
#pragma unroll
      for (int off = 1; off < 16; off <<= 1) mx = fmaxf(mx, __shfl_xor(mx, off));
      float mn = fmaxf(Mrow[i], mx);
      float al = __expf(Mrow[i] - mn);
      Mrow[i] = mn;
      f32x4 p;
      float s = 0.f;
#pragma unroll
      for (int nn = 0; nn < 4; ++nn) {
        p[nn] = __expf(S[i][nn] - mn);
        s += p[nn];
      }
#pragma unroll
      for (int off = 1; off < 16; off <<= 1) s += __shfl_xor(s, off);
      Lrow[i] = Lrow[i] * al + s;
      *(f32x4*)&P_s[(ty + 16 * i) * 68 + tx * 4] = p;
#pragma unroll
      for (int j = 0; j < 8; ++j) hacc[i][j] *= al;
    }
    __syncthreads();

    for (int n4 = 0; n4 < 64; n4 += 4) {
      f32x4 p4[8], x4[8];
#pragma unroll
      for (int i = 0; i < 8; ++i) p4[i] = *(f32x4*)&P_s[(ty + 16 * i) * 68 + n4];
#pragma unroll
      for (int j = 0; j < 8; ++j) x4[j] = *(f32x4*)&xs_s[(tx + 16 * j) * 68 + n4];
#pragma unroll
      for (int i = 0; i < 8; ++i)
#pragma unroll
        for (int j = 0; j < 8; ++j) {
          hacc[i][j] += p4[i][0] * x4[j][0];
          hacc[i][j] += p4[i][1] * x4[j][1];
          hacc[i][j] += p4[i][2] * x4[j][2];
          hacc[i][j] += p4[i][3] * x4[j][3];
        }
    }
  }

  const size_t sb = (size_t)seg * 32 + b;
#pragma unroll
  for (int i = 0; i < 8; ++i) {
    const int m = m0 + ty + 16 * i;
    if (tx == 0) {
      ml[(sb * 512 + m) * 2] = Mrow[i];
      ml[(sb * 512 + m) * 2 + 1] = Lrow[i];
    }
#pragma unroll
    for (int j = 0; j < 8; ++j)
      h_part[(sb * 512 + m) * 128 + tx + 16 * j] = hacc[i][j];
  }
}

// ---------------------------------------------------------------------------
// Combine 4 n-segments — unchanged.
// ---------------------------------------------------------------------------
__global__ __launch_bounds__(128) void k_combine(const float* __restrict__ h_part,
                                                 const float* __restrict__ ml,
                                                 float* __restrict__ hbuf) {
  const int mb = blockIdx.x;
  const int m = mb >> 5, b = mb & 31;
  const int c = threadIdx.x;
  float Ms[4], M = NEG_INF;
#pragma unroll
  for (int s = 0; s < 4; ++s) {
    Ms[s] = ml[(((size_t)s * 32 + b) * 512 + m) * 2];
    M = fmaxf(M, Ms[s]);
  }
  float w[4], L = 0.f;
#pragma unroll
  for (int s = 0; s < 4; ++s) {
    w[s] = __expf(Ms[s] - M);
    L += w[s] * ml[(((size_t)s * 32 + b) * 512 + m) * 2 + 1];
  }
  float acc = 0.f;
#pragma unroll
  for (int s = 0; s < 4; ++s)
    acc += w[s] * h_part[(((size_t)s * 32 + b) * 512 + m) * 128 + c];
  hbuf[(size_t)m * 4096 + b * 128 + c] = acc / L;
}

// ---------------------------------------------------------------------------
// Split Wf (fp32) -> hi/lo bf16, same [l][o][m] layout.
// ---------------------------------------------------------------------------
__global__ __launch_bounds__(256) void k_wsplit(const float* __restrict__ W,
                                                bf16_t* __restrict__ hi,
                                                bf16_t* __restrict__ lo) {
  const size_t i4 = ((size_t)blockIdx.x * 256 + threadIdx.x) * 4;
  f32x4 v = *(const f32x4*)&W[i4];
  bf16x4 h4, l4;
#pragma unroll
  for (int k = 0; k < 4; ++k) {
    bf16_t h = (bf16_t)v[k];
    h4[k] = h;
    l4[k] = (bf16_t)(v[k] - (float)h);
  }
  *(bf16x4*)&hi[i4] = h4;
  *(bf16x4*)&lo[i4] = l4;
}

// ---------------------------------------------------------------------------
// h [512m][4096bc] fp32 -> hT hi/lo bf16 [4096bc][512m].  64x64 tiles.
// ---------------------------------------------------------------------------
__global__ __launch_bounds__(256) void k_hsplit(const float* __restrict__ h,
                                                bf16_t* __restrict__ thi,
                                                bf16_t* __restrict__ tlo) {
  __shared__ float T[64 * 65];  // [c][m]
  const int m0 = blockIdx.x * 64, c0 = blockIdx.y * 64;
  const int t = threadIdx.x;
#pragma unroll
  for (int ii = 0; ii < 4; ++ii) {
    int slot = ii * 256 + t;
    int m = slot >> 4, c4 = (slot & 15) * 4;
    f32x4 v = *(const f32x4*)&h[(size_t)(m0 + m) * 4096 + c0 + c4];
#pragma unroll
    for (int k = 0; k < 4; ++k) T[(c4 + k) * 65 + m] = v[k];
  }
  __syncthreads();
  const int row = t >> 2, mg = (t & 3) * 16;
  bf16x8 h8[2], l8[2];
#pragma unroll
  for (int half = 0; half < 2; ++half)
#pragma unroll
    for (int j = 0; j < 8; ++j) {
      float v = T[row * 65 + mg + half * 8 + j];
      bf16_t hh = (bf16_t)v;
      h8[half][j] = hh;
      l8[half][j] = (bf16_t)(v - (float)hh);
    }
  bf16_t* ph = &thi[(size_t)(c0 + row) * 512 + m0 + mg];
  bf16_t* pl = &tlo[(size_t)(c0 + row) * 512 + m0 + mg];
  *(bf16x8*)ph = h8[0];
  *(bf16x8*)(ph + 8) = h8[1];
  *(bf16x8*)pl = l8[0];
  *(bf16x8*)(pl + 8) = l8[1];
}

// ---------------------------------------------------------------------------
// h [512m][4096bc] fp32 -> hbufT fp32 [4096bc][512m].  64x64 tiles.
// ---------------------------------------------------------------------------
__global__ __launch_bounds__(256) void k_htrans(const float* __restrict__ h,
                                                float* __restrict__ hT) {
  __shared__ float T[64 * 65];
  const int m0 = blockIdx.x * 64, c0 = blockIdx.y * 64;
  const int t = threadIdx.x;
#pragma unroll
  for (int ii = 0; ii < 4; ++ii) {
    int slot = ii * 256 + t;
    int m = slot >> 4, c4 = (slot & 15) * 4;
    f32x4 v = *(const f32x4*)&h[(size_t)(m0 + m) * 4096 + c0 + c4];
#pragma unroll
    for (int k = 0; k < 4; ++k) T[(c4 + k) * 65 + m] = v[k];
  }
  __syncthreads();
  const int row = t >> 2, mg = (t & 3) * 16;
#pragma unroll
  for (int g = 0; g < 4; ++g) {
    f32x4 v;
#pragma unroll
    for (int k = 0; k < 4; ++k) v[k] = T[row * 65 + mg + g * 4 + k];
    *(f32x4*)&hT[(size_t)(c0 + row) * 512 + m0 + mg + g * 4] = v;
  }
}

// ---------------------------------------------------------------------------
// Layer GEMM via split-bf16 MFMA: y[o][bc] = Wf[l] @ h  (+ per-o sum/sumsq).
// grid (16 o-tiles of 32, 32 bc-tiles of 128); wave w owns bc quarter (32).
// Wave tile 32o x 32bc = 2x2 subtiles of 16x16, K-step 32.
// A-frag: Whi/Wlo rows (o, k contiguous).  B-frag: hThi/hTlo rows (bc, k).
// D = A · B^T  (both operands row-major K-contiguous).
// ---------------------------------------------------------------------------
__global__ __launch_bounds__(256) void k_layerA(const bf16_t* __restrict__ Whi,
                                                const bf16_t* __restrict__ Wlo,
                                                const bf16_t* __restrict__ hThi,
                                                const bf16_t* __restrict__ hTlo,
                                                int l, float* __restrict__ ybuf,
                                                float* __restrict__ stats) {
  const int o0 = blockIdx.x * 32;
  const int bc0 = blockIdx.y * 128;
  const int t = threadIdx.x;
  const int w = t >> 6, lane = t & 63, l15 = lane & 15, q = lane >> 4;
  const int bcw = bc0 + w * 32;
  const bf16_t* Wh = Whi + (size_t)l * M_ * M_;
  const bf16_t* Wl = Wlo + (size_t)l * M_ * M_;

  f32x4 acc[2][2];
#pragma unroll
  for (int i = 0; i < 2; ++i)
#pragma unroll
    for (int j = 0; j < 2; ++j) acc[i][j] = f32x4{0.f, 0.f, 0.f, 0.f};

  for (int k0 = 0; k0 < M_; k0 += 32) {
    bf16x8 ah[2], al[2], bh[2], bl[2];
#pragma unroll
    for (int os = 0; os < 2; ++os) {
      const size_t ro = (size_t)(o0 + os * 16 + l15) * M_ + k0 + q * 8;
      ah[os] = *(const bf16x8*)&Wh[ro];
      al[os] = *(const bf16x8*)&Wl[ro];
    }
#pragma unroll
    for (int ns = 0; ns < 2; ++ns) {
      const size_t rb = (size_t)(bcw + ns * 16 + l15) * M_ + k0 + q * 8;
      bh[ns] = *(const bf16x8*)&hThi[rb];
      bl[ns] = *(const bf16x8*)&hTlo[rb];
    }
#pragma unroll
    for (int os = 0; os < 2; ++os)
#pragma unroll
      for (int ns = 0; ns < 2; ++ns) {
        acc[os][ns] = MFMA16(ah[os], bh[ns], acc[os][ns]);
        acc[os][ns] = MFMA16(ah[os], bl[ns], acc[os][ns]);
        acc[os][ns] = MFMA16(al[os], bh[ns], acc[os][ns]);
      }
  }

  // epilogue: store y, reduce sum/sumsq over bc
  float s1[2][4], s2[2][4];
#pragma unroll
  for (int os = 0; os < 2; ++os)
#pragma unroll
    for (int r = 0; r < 4; ++r) {
      float a = 0.f, b2 = 0.f;
#pragma unroll
      for (int ns = 0; ns < 2; ++ns) {
        float v = acc[os][ns][r];
        ybuf[(size_t)(o0 + os * 16 + q * 4 + r) * 4096 + bcw + ns * 16 + l15] = v;
        a += v;
        b2 += v * v;
      }
      s1[os][r] = a;
      s2[os][r] = b2;
    }
#pragma unroll
  for (int os = 0; os < 2; ++os)
#pragma unroll
    for (int r = 0; r < 4; ++r) {
#pragma unroll
      for (int off = 1; off < 16; off <<= 1) {
        s1[os][r] += __shfl_xor(s1[os][r], off);
        s2[os][r] += __shfl_xor(s2[os][r], off);
      }
      if (l15 == 0) {
        const int o = o0 + os * 16 + q * 4 + r;
        atomicAdd(&stats[l * 1024 + o], s1[os][r]);
        atomicAdd(&stats[l * 1024 + 512 + o], s2[os][r]);
      }
    }
}

// ---------------------------------------------------------------------------
// BN + residual + relu elementwise — unchanged.
// ---------------------------------------------------------------------------
__global__ __launch_bounds__(256) void k_layerB(const float* __restrict__ ybuf,
                                                float* __restrict__ hbuf,
                                                const float* __restrict__ stats,
                                                const float* __restrict__ gamma,
                                                const float* __restrict__ beta, int l) {
  const size_t i4 = ((size_t)blockIdx.x * 256 + threadIdx.x) * 4;
  const int o = (int)(i4 >> 12);
  f32x4 y = *(const f32x4*)&ybuf[i4];
  f32x4 h = *(const f32x4*)&hbuf[i4];
  const float mu = stats[l * 1024 + o] * (1.f / 4096.f);
  const float var = stats[l * 1024 + 512 + o] * (1.f / 4096.f) - mu * mu;
  const float rs = rsqrtf(var + 1e-5f);
  const float g = gamma[l * 512 + o];
  const float bt = beta[l * 512 + o];
  f32x4 r;
#pragma unroll
  for (int jj = 0; jj < 4; ++jj)
    r[jj] = fmaxf((y[jj] - mu) * rs * g + bt + h[jj], 0.f);
  *(f32x4*)&hbuf[i4] = r;
}

// ---------------------------------------------------------------------------
// Unpool v2 (flash over m): logits register-tiled from global; P and x1 tile
// staged in LDS m-contiguous; apply = vectorized LDS-fed register GEMM.
// grid (32 n-tiles of 128, 32 b), 256 thr.
// logits mapping: m = mc0+tx*4+i, n = ty*8+j.  apply: c = ty+16i, n = tx+16j.
// ---------------------------------------------------------------------------
__global__ __launch_bounds__(256) void k_unpool(const float* __restrict__ xs,
                                                const float* __restrict__ Wun,
                                                const float* __restrict__ bun,
                                                const float* __restrict__ hbufT,
                                                float* __restrict__ out) {
  __shared__ float P_s[128 * 68];   // [n][m] m-stride 68
  __shared__ float h_s[128 * 68];   // [c][m] m-stride 68
  __shared__ float alpha_s[128];
  __shared__ float L_s[128];
  const int n0 = blockIdx.x * 128;
  const int b = blockIdx.y;
  const int t = threadIdx.x, ty = t >> 4, tx = t & 15;
  const float* xsb = xs + (size_t)b * C_ * N_;

  float acc[8][8];
#pragma unroll
  for (int i = 0; i < 8; ++i)
#pragma unroll
    for (int j = 0; j < 8; ++j) acc[i][j] = 0.f;
  float Mn[8], Ln[8];
#pragma unroll
  for (int j = 0; j < 8; ++j) {
    Mn[j] = NEG_INF;
    Ln[j] = 0.f;
  }

  for (int ch = 0; ch < 8; ++ch) {
    const int mc0 = ch * 64;
    // ---- logits (registers only) ----
    f32x4 ulv[4][2];
#pragma unroll
    for (int i = 0; i < 4; ++i) {
      const float bi = bun[mc0 + tx * 4 + i];
      ulv[i][0] = f32x4{bi, bi, bi, bi};
      ulv[i][1] = f32x4{bi, bi, bi, bi};
    }
    for (int c4 = 0; c4 < 128; c4 += 4) {
      f32x4 a4[4];
#pragma unroll
      for (int i = 0; i < 4; ++i)
        a4[i] = *(const f32x4*)&Wun[(size_t)(mc0 + tx * 4 + i) * 128 + c4];
#pragma unroll
      for (int cc = 0; cc < 4; ++cc) {
        const float* xp = &xsb[(size_t)(c4 + cc) * N_ + n0 + ty * 8];
        f32x4 xv0 = *(const f32x4*)xp;
        f32x4 xv1 = *(const f32x4*)(xp + 4);
#pragma unroll
        for (int i = 0; i < 4; ++i) {
          ulv[i][0] += a4[i][cc] * xv0;
          ulv[i][1] += a4[i][cc] * xv1;
        }
      }
    }
    // ---- online softmax over m (regs; shfl over tx) ----
    float pv[4][8], alj[8];
#pragma unroll
    for (int j = 0; j < 8; ++j) {
      float u0 = ulv[0][j >> 2][j & 3], u1 = ulv[1][j >> 2][j & 3];
      float u2 = ulv[2][j >> 2][j & 3], u3 = ulv[3][j >> 2][j & 3];
      float mx = fmaxf(fmaxf(u0, u1), fmaxf(u2, u3));
#pragma unroll
      for (int off = 1; off < 16; off <<= 1) mx = fmaxf(mx, __shfl_xor(mx, off));
      float mn = fmaxf(Mn[j], mx);
      alj[j] = __expf(Mn[j] - mn);
      Mn[j] = mn;
      pv[0][j] = __expf(u0 - mn);
      pv[1][j] = __expf(u1 - mn);
      pv[2][j] = __expf(u2 - mn);
      pv[3][j] = __expf(u3 - mn);
      float s = pv[0][j] + pv[1][j] + pv[2][j] + pv[3][j];
#pragma unroll
      for (int off = 1; off < 16; off <<= 1) s += __shfl_xor(s, off);
      Ln[j] = Ln[j] * alj[j] + s;
    }
    __syncthreads();  // protect previous chunk's apply reads
    // ---- write P (m-contiguous), alpha, L; stage x1 tile ----
#pragma unroll
    for (int j = 0; j < 8; ++j) {
      f32x4 p4 = f32x4{pv[0][j], pv[1][j], pv[2][j], pv[3][j]};
      *(f32x4*)&P_s[(ty * 8 + j) * 68 + tx * 4] = p4;
    }
    if (tx == 0) {
#pragma unroll
      for (int j = 0; j < 8; ++j) {
        alpha_s[ty * 8 + j] = alj[j];
        L_s[ty * 8 + j] = Ln[j];
      }
    }
#pragma unroll
    for (int ii = 0; ii < 8; ++ii) {
      int slot = ii * 256 + t;
      int c = slot >> 4, m4 = (slot & 15) * 4;
      *(f32x4*)&h_s[c * 68 + m4] =
          *(const f32x4*)&hbufT[((size_t)b * 128 + c) * 512 + mc0 + m4];
    }
    __syncthreads();
    // ---- apply: acc[c][n] = acc*alpha + sum_m h[c][m] P[n][m] ----
    {
      float al8[8];
#pragma unroll
      for (int j = 0; j < 8; ++j) al8[j] = alpha_s[tx + 16 * j];
#pragma unroll
      for (int i = 0; i < 8; ++i)
#pragma unroll
        for (int j = 0; j < 8; ++j) acc[i][j] *= al8[j];
    }
    for (int m4 = 0; m4 < 64; m4 += 4) {
      f32x4 hv[8], pw[8];
#pragma unroll
      for (int i = 0; i < 8; ++i) hv[i] = *(f32x4*)&h_s[(ty + 16 * i) * 68 + m4];
#pragma unroll
      for (int j = 0; j < 8; ++j) pw[j] = *(f32x4*)&P_s[(tx + 16 * j) * 68 + m4];
#pragma unroll
      for (int i = 0; i < 8; ++i)
#pragma unroll
        for (int j = 0; j < 8; ++j) {
          acc[i][j] += hv[i][0] * pw[j][0];
          acc[i][j] += hv[i][1] * pw[j][1];
          acc[i][j] += hv[i][2] * pw[j][2];
          acc[i][j] += hv[i][3] * pw[j][3];
        }
    }
  }

  float inv[8];
#pragma unroll
  for (int j = 0; j < 8; ++j) inv[j] = 1.f / L_s[tx + 16 * j];
#pragma unroll
  for (int i = 0; i < 8; ++i)
#pragma unroll
    for (int j = 0; j < 8; ++j)
      out[((size_t)b * 128 + ty + 16 * i) * (size_t)N_ + n0 + tx + 16 * j] =
          acc[i][j] * inv[j];
}

// ---------------------------------------------------------------------------
extern "C" void kernel_launch(void* const* d_in, const int* in_sizes, int n_in,
                              void* d_out, int out_size, void* d_ws, size_t ws_size,
                              hipStream_t stream) {
  const float* x = (const float*)d_in[0];
  const float* W_pool = (const float*)d_in[1];
  const float* Wf = (const float*)d_in[2];
  const float* gamma = (const float*)d_in[3];
  const float* beta = (const float*)d_in[4];
  const float* W_unpool = (const float*)d_in[5];
  const float* b_unpool = (const float*)d_in[6];
  float* out = (float*)d_out;

  char* ws = (char*)d_ws;
  float* h_part = (float*)ws; ws += (size_t)4 * 32 * 512 * 128 * 4;  // 33.6 MB
  float* ml = (float*)ws;     ws += (size_t)4 * 32 * 512 * 2 * 4;    // 0.5 MB
  float* hbuf = (float*)ws;   ws += (size_t)512 * 4096 * 4;          // 8.4 MB
  float* stats = (float*)ws;  ws += NL * 1024 * 4;
  // aliased into h_part (dead after k_combine):
  char* hp = (char*)h_part;
  float* ybuf = (float*)(hp);                                   // 8.39 MB
  float* hbufT = (float*)(hp + 8388608);                        // 8.39 MB
  bf16_t* Whi = (bf16_t*)(hp + 16777216);                       // 3.15 MB
  bf16_t* Wlo = (bf16_t*)(hp + 19922944);                       // 3.15 MB
  bf16_t* hThi = (bf16_t*)(hp + 23068672);                      // 4.19 MB
  bf16_t* hTlo = (bf16_t*)(hp + 27262976);                      // 4.19 MB

  hipMemsetAsync(stats, 0, NL * 1024 * 4, stream);
  k_pool<<<dim3(16, 32), 256, 0, stream>>>(x, W_pool, h_part, ml);
  k_combine<<<dim3(16384), 128, 0, stream>>>(h_part, ml, hbuf);
  k_wsplit<<<dim3(1536), 256, 0, stream>>>(Wf, Whi, Wlo);
  k_hsplit<<<dim3(8, 64), 256, 0, stream>>>(hbuf, hThi, hTlo);
  for (int l = 0; l < NL; ++l) {
    k_layerA<<<dim3(16, 32), 256, 0, stream>>>(Whi, Wlo, hThi, hTlo, l, ybuf, stats);
    k_layerB<<<dim3(2048), 256, 0, stream>>>(ybuf, hbuf, stats, gamma, beta, l);
    if (l < NL - 1)
      k_hsplit<<<dim3(8, 64), 256, 0, stream>>>(hbuf, hThi, hTlo);
  }
  k_htrans<<<dim3(8, 64), 256, 0, stream>>>(hbuf, hbufT);
  k_unpool<<<dim3(32, 32), 256, 0, stream>>>(x, W_unpool, b_unpool, hbufT, out);
}

// Round 4
// 1095.254 us; speedup vs baseline: 2.0916x; 1.5340x over previous
//
#include <hip/hip_runtime.h>
#include <hip/hip_bf16.h>

typedef float f32x4 __attribute__((ext_vector_type(4)));
typedef __bf16 bf16_t;
typedef __bf16 bf16x4 __attribute__((ext_vector_type(4)));
typedef __bf16 bf16x8 __attribute__((ext_vector_type(8)));

#define MFMA16(a, b, c) __builtin_amdgcn_mfma_f32_16x16x32_bf16(a, b, c, 0, 0, 0)

constexpr int C_ = 128;
constexpr int N_ = 4096;
constexpr int M_ = 512;
constexpr int NL = 6;

#define NEG_INF (-__builtin_huge_valf())

// ---------------------------------------------------------------------------
// Pool (flash over n) — unchanged.
// ---------------------------------------------------------------------------
__global__ __launch_bounds__(256) void k_pool(const float* __restrict__ xs,
                                              const float* __restrict__ Wp,
                                              float* __restrict__ h_part,
                                              float* __restrict__ ml) {
  __shared__ float xs_s[128 * 68];
  __shared__ float P_s[128 * 68];
  const int bx = blockIdx.x;
  const int b = blockIdx.y;
  const int mt = bx >> 2, seg = bx & 3;
  const int m0 = mt * 128;
  const int t = threadIdx.x, ty = t >> 4, tx = t & 15;
  const float* xsb = xs + (size_t)b * C_ * N_;

  float Mrow[8], Lrow[8], hacc[8][8];
#pragma unroll
  for (int i = 0; i < 8; ++i) {
    Mrow[i] = NEG_INF;
    Lrow[i] = 0.f;
#pragma unroll
    for (int j = 0; j < 8; ++j) hacc[i][j] = 0.f;
  }

  for (int ch = 0; ch < 16; ++ch) {
    const int n0 = seg * 1024 + ch * 64;
    __syncthreads();
#pragma unroll
    for (int ii = 0; ii < 8; ++ii) {
      int f = ii * 1024 + t * 4;
      int c = f >> 6, n = f & 63;
      *(f32x4*)&xs_s[c * 68 + n] = *(const f32x4*)&xsb[(size_t)c * N_ + n0 + n];
    }
    __syncthreads();

    f32x4 S[8];
#pragma unroll
    for (int i = 0; i < 8; ++i) S[i] = f32x4{0.f, 0.f, 0.f, 0.f};
    for (int c4 = 0; c4 < 128; c4 += 4) {
      f32x4 a4[8];
#pragma unroll
      for (int i = 0; i < 8; ++i)
        a4[i] = *(const f32x4*)&Wp[(size_t)(m0 + ty + 16 * i) * 128 + c4];
#pragma unroll
      for (int cc = 0; cc < 4; ++cc) {
        f32x4 b4 = *(f32x4*)&xs_s[(c4 + cc) * 68 + tx * 4];
#pragma unroll
        for (int i = 0; i < 8; ++i) S[i] += a4[i][cc] * b4;
      }
    }

#pragma unroll
    for (int i = 0; i < 8; ++i) {
      float mx = fmaxf(fmaxf(S[i][0], S[i][1]), fmaxf(S[i][2], S[i][3]));
#pragma unroll
      for (int off = 1; off < 16; off <<= 1) mx = fmaxf(mx, __shfl_xor(mx, off));
      float mn = fmaxf(Mrow[i], mx);
      float al = __expf(Mrow[i] - mn);
      Mrow[i] = mn;
      f32x4 p;
      float s = 0.f;
#pragma unroll
      for (int nn = 0; nn < 4; ++nn) {
        p[nn] = __expf(S[i][nn] - mn);
        s += p[nn];
      }
#pragma unroll
      for (int off = 1; off < 16; off <<= 1) s += __shfl_xor(s, off);
      Lrow[i] = Lrow[i] * al + s;
      *(f32x4*)&P_s[(ty + 16 * i) * 68 + tx * 4] = p;
#pragma unroll
      for (int j = 0; j < 8; ++j) hacc[i][j] *= al;
    }
    __syncthreads();

    for (int n4 = 0; n4 < 64; n4 += 4) {
      f32x4 p4[8], x4[8];
#pragma unroll
      for (int i = 0; i < 8; ++i) p4[i] = *(f32x4*)&P_s[(ty + 16 * i) * 68 + n4];
#pragma unroll
      for (int j = 0; j < 8; ++j) x4[j] = *(f32x4*)&xs_s[(tx + 16 * j) * 68 + n4];
#pragma unroll
      for (int i = 0; i < 8; ++i)
#pragma unroll
        for (int j = 0; j < 8; ++j) {
          hacc[i][j] += p4[i][0] * x4[j][0];
          hacc[i][j] += p4[i][1] * x4[j][1];
          hacc[i][j] += p4[i][2] * x4[j][2];
          hacc[i][j] += p4[i][3] * x4[j][3];
        }
    }
  }

  const size_t sb = (size_t)seg * 32 + b;
#pragma unroll
  for (int i = 0; i < 8; ++i) {
    const int m = m0 + ty + 16 * i;
    if (tx == 0) {
      ml[(sb * 512 + m) * 2] = Mrow[i];
      ml[(sb * 512 + m) * 2 + 1] = Lrow[i];
    }
#pragma unroll
    for (int j = 0; j < 8; ++j)
      h_part[(sb * 512 + m) * 128 + tx + 16 * j] = hacc[i][j];
  }
}

// ---------------------------------------------------------------------------
// Combine 4 n-segments — unchanged.
// ---------------------------------------------------------------------------
__global__ __launch_bounds__(128) void k_combine(const float* __restrict__ h_part,
                                                 const float* __restrict__ ml,
                                                 float* __restrict__ hbuf) {
  const int mb = blockIdx.x;
  const int m = mb >> 5, b = mb & 31;
  const int c = threadIdx.x;
  float Ms[4], M = NEG_INF;
#pragma unroll
  for (int s = 0; s < 4; ++s) {
    Ms[s] = ml[(((size_t)s * 32 + b) * 512 + m) * 2];
    M = fmaxf(M, Ms[s]);
  }
  float w[4], L = 0.f;
#pragma unroll
  for (int s = 0; s < 4; ++s) {
    w[s] = __expf(Ms[s] - M);
    L += w[s] * ml[(((size_t)s * 32 + b) * 512 + m) * 2 + 1];
  }
  float acc = 0.f;
#pragma unroll
  for (int s = 0; s < 4; ++s)
    acc += w[s] * h_part[(((size_t)s * 32 + b) * 512 + m) * 128 + c];
  hbuf[(size_t)m * 4096 + b * 128 + c] = acc / L;
}

// ---------------------------------------------------------------------------
// Split fp32 array -> hi/lo bf16 (same layout). 1024 elems per block.
// ---------------------------------------------------------------------------
__global__ __launch_bounds__(256) void k_wsplit(const float* __restrict__ W,
                                                bf16_t* __restrict__ hi,
                                                bf16_t* __restrict__ lo) {
  const size_t i4 = ((size_t)blockIdx.x * 256 + threadIdx.x) * 4;
  f32x4 v = *(const f32x4*)&W[i4];
  bf16x4 h4, l4;
#pragma unroll
  for (int k = 0; k < 4; ++k) {
    bf16_t h = (bf16_t)v[k];
    h4[k] = h;
    l4[k] = (bf16_t)(v[k] - (float)h);
  }
  *(bf16x4*)&hi[i4] = h4;
  *(bf16x4*)&lo[i4] = l4;
}

// ---------------------------------------------------------------------------
// xs [b][c][n] fp32 -> xsThi/xsTlo [b][n][c] bf16 (transpose + split).
// grid (64 n-tiles of 64, 32 b).
// ---------------------------------------------------------------------------
__global__ __launch_bounds__(256) void k_xsplit(const float* __restrict__ xs,
                                                bf16_t* __restrict__ thi,
                                                bf16_t* __restrict__ tlo) {
  __shared__ float T[128 * 68];  // [c][n]
  const int n0 = blockIdx.x * 64, b = blockIdx.y;
  const int t = threadIdx.x;
  const float* xsb = xs + (size_t)b * C_ * N_;
#pragma unroll
  for (int i = 0; i < 8; ++i) {
    int slot = i * 256 + t;  // 0..2047
    int c = slot >> 4, n4 = (slot & 15) * 4;
    *(f32x4*)&T[c * 68 + n4] = *(const f32x4*)&xsb[(size_t)c * N_ + n0 + n4];
  }
  __syncthreads();
  const int n = t >> 2, cb = (t & 3) * 32;
  bf16x8 h8[4], l8[4];
#pragma unroll
  for (int g = 0; g < 4; ++g)
#pragma unroll
    for (int j = 0; j < 8; ++j) {
      float v = T[(cb + g * 8 + j) * 68 + n];
      bf16_t hh = (bf16_t)v;
      h8[g][j] = hh;
      l8[g][j] = (bf16_t)(v - (float)hh);
    }
  const size_t base = ((size_t)b * N_ + n0 + n) * C_ + cb;
#pragma unroll
  for (int g = 0; g < 4; ++g) {
    *(bf16x8*)&thi[base + g * 8] = h8[g];
    *(bf16x8*)&tlo[base + g * 8] = l8[g];
  }
}

// ---------------------------------------------------------------------------
// h [512m][4096bc] fp32 -> hT hi/lo bf16 [4096bc][512m].  64x64 tiles.
// ---------------------------------------------------------------------------
__global__ __launch_bounds__(256) void k_hsplit(const float* __restrict__ h,
                                                bf16_t* __restrict__ thi,
                                                bf16_t* __restrict__ tlo) {
  __shared__ float T[64 * 65];  // [c][m]
  const int m0 = blockIdx.x * 64, c0 = blockIdx.y * 64;
  const int t = threadIdx.x;
#pragma unroll
  for (int ii = 0; ii < 4; ++ii) {
    int slot = ii * 256 + t;
    int m = slot >> 4, c4 = (slot & 15) * 4;
    f32x4 v = *(const f32x4*)&h[(size_t)(m0 + m) * 4096 + c0 + c4];
#pragma unroll
    for (int k = 0; k < 4; ++k) T[(c4 + k) * 65 + m] = v[k];
  }
  __syncthreads();
  const int row = t >> 2, mg = (t & 3) * 16;
  bf16x8 h8[2], l8[2];
#pragma unroll
  for (int half = 0; half < 2; ++half)
#pragma unroll
    for (int j = 0; j < 8; ++j) {
      float v = T[row * 65 + mg + half * 8 + j];
      bf16_t hh = (bf16_t)v;
      h8[half][j] = hh;
      l8[half][j] = (bf16_t)(v - (float)hh);
    }
  bf16_t* ph = &thi[(size_t)(c0 + row) * 512 + m0 + mg];
  bf16_t* pl = &tlo[(size_t)(c0 + row) * 512 + m0 + mg];
  *(bf16x8*)ph = h8[0];
  *(bf16x8*)(ph + 8) = h8[1];
  *(bf16x8*)pl = l8[0];
  *(bf16x8*)(pl + 8) = l8[1];
}

// ---------------------------------------------------------------------------
// Layer GEMM via split-bf16 MFMA — unchanged.
// ---------------------------------------------------------------------------
__global__ __launch_bounds__(256) void k_layerA(const bf16_t* __restrict__ Whi,
                                                const bf16_t* __restrict__ Wlo,
                                                const bf16_t* __restrict__ hThi,
                                                const bf16_t* __restrict__ hTlo,
                                                int l, float* __restrict__ ybuf,
                                                float* __restrict__ stats) {
  const int o0 = blockIdx.x * 32;
  const int bc0 = blockIdx.y * 128;
  const int t = threadIdx.x;
  const int w = t >> 6, lane = t & 63, l15 = lane & 15, q = lane >> 4;
  const int bcw = bc0 + w * 32;
  const bf16_t* Wh = Whi + (size_t)l * M_ * M_;
  const bf16_t* Wl = Wlo + (size_t)l * M_ * M_;

  f32x4 acc[2][2];
#pragma unroll
  for (int i = 0; i < 2; ++i)
#pragma unroll
    for (int j = 0; j < 2; ++j) acc[i][j] = f32x4{0.f, 0.f, 0.f, 0.f};

  for (int k0 = 0; k0 < M_; k0 += 32) {
    bf16x8 ah[2], al[2], bh[2], bl[2];
#pragma unroll
    for (int os = 0; os < 2; ++os) {
      const size_t ro = (size_t)(o0 + os * 16 + l15) * M_ + k0 + q * 8;
      ah[os] = *(const bf16x8*)&Wh[ro];
      al[os] = *(const bf16x8*)&Wl[ro];
    }
#pragma unroll
    for (int ns = 0; ns < 2; ++ns) {
      const size_t rb = (size_t)(bcw + ns * 16 + l15) * M_ + k0 + q * 8;
      bh[ns] = *(const bf16x8*)&hThi[rb];
      bl[ns] = *(const bf16x8*)&hTlo[rb];
    }
#pragma unroll
    for (int os = 0; os < 2; ++os)
#pragma unroll
      for (int ns = 0; ns < 2; ++ns) {
        acc[os][ns] = MFMA16(ah[os], bh[ns], acc[os][ns]);
        acc[os][ns] = MFMA16(ah[os], bl[ns], acc[os][ns]);
        acc[os][ns] = MFMA16(al[os], bh[ns], acc[os][ns]);
      }
  }

  float s1[2][4], s2[2][4];
#pragma unroll
  for (int os = 0; os < 2; ++os)
#pragma unroll
    for (int r = 0; r < 4; ++r) {
      float a = 0.f, b2 = 0.f;
#pragma unroll
      for (int ns = 0; ns < 2; ++ns) {
        float v = acc[os][ns][r];
        ybuf[(size_t)(o0 + os * 16 + q * 4 + r) * 4096 + bcw + ns * 16 + l15] = v;
        a += v;
        b2 += v * v;
      }
      s1[os][r] = a;
      s2[os][r] = b2;
    }
#pragma unroll
  for (int os = 0; os < 2; ++os)
#pragma unroll
    for (int r = 0; r < 4; ++r) {
#pragma unroll
      for (int off = 1; off < 16; off <<= 1) {
        s1[os][r] += __shfl_xor(s1[os][r], off);
        s2[os][r] += __shfl_xor(s2[os][r], off);
      }
      if (l15 == 0) {
        const int o = o0 + os * 16 + q * 4 + r;
        atomicAdd(&stats[l * 1024 + o], s1[os][r]);
        atomicAdd(&stats[l * 1024 + 512 + o], s2[os][r]);
      }
    }
}

// ---------------------------------------------------------------------------
// BN + residual + relu elementwise — unchanged.
// ---------------------------------------------------------------------------
__global__ __launch_bounds__(256) void k_layerB(const float* __restrict__ ybuf,
                                                float* __restrict__ hbuf,
                                                const float* __restrict__ stats,
                                                const float* __restrict__ gamma,
                                                const float* __restrict__ beta, int l) {
  const size_t i4 = ((size_t)blockIdx.x * 256 + threadIdx.x) * 4;
  const int o = (int)(i4 >> 12);
  f32x4 y = *(const f32x4*)&ybuf[i4];
  f32x4 h = *(const f32x4*)&hbuf[i4];
  const float mu = stats[l * 1024 + o] * (1.f / 4096.f);
  const float var = stats[l * 1024 + 512 + o] * (1.f / 4096.f) - mu * mu;
  const float rs = rsqrtf(var + 1e-5f);
  const float g = gamma[l * 512 + o];
  const float bt = beta[l * 512 + o];
  f32x4 r;
#pragma unroll
  for (int jj = 0; jj < 4; ++jj)
    r[jj] = fmaxf((y[jj] - mu) * rs * g + bt + h[jj], 0.f);
  *(f32x4*)&hbuf[i4] = r;
}

// ---------------------------------------------------------------------------
// Unpool v3 (MFMA flash over m).  grid (64 n-tiles of 64, 32 b), 4 waves.
// Logits: U[64m][64n] = Wun·xsT^T (split-bf16, LDS B-frags).  Block-wide
// online column softmax.  Apply: out[128c][64n] += x1·P^T (split-bf16).
// ---------------------------------------------------------------------------
__global__ __launch_bounds__(256) void k_unpool(const bf16_t* __restrict__ xsThi,
                                                const bf16_t* __restrict__ xsTlo,
                                                const bf16_t* __restrict__ Wuh,
                                                const bf16_t* __restrict__ Wul,
                                                const float* __restrict__ bun,
                                                const bf16_t* __restrict__ x1hi,
                                                const bf16_t* __restrict__ x1lo,
                                                float* __restrict__ out) {
  __shared__ bf16_t XH[64 * 136], XL[64 * 136];   // xsT tile [n][c]
  __shared__ bf16_t PH[64 * 72], PL[64 * 72];     // P^T [n][m-local]
  __shared__ float colmax_s[4][64], colsum_s[4][64];
  __shared__ float M_s[64], L_s[64], alpha_s[64];
  const int n0 = blockIdx.x * 64, b = blockIdx.y;
  const int t = threadIdx.x, w = t >> 6, lane = t & 63, l15 = lane & 15, q = lane >> 4;

  // stage xsT tile (hi/lo)
#pragma unroll
  for (int i = 0; i < 4; ++i) {
    int slot = i * 256 + t;  // 0..1023
    int n = slot >> 4, cg = (slot & 15) * 8;
    const size_t g = ((size_t)b * N_ + n0 + n) * C_ + cg;
    *(bf16x8*)&XH[n * 136 + cg] = *(const bf16x8*)&xsThi[g];
    *(bf16x8*)&XL[n * 136 + cg] = *(const bf16x8*)&xsTlo[g];
  }
  if (t < 64) {
    M_s[t] = NEG_INF;
    L_s[t] = 0.f;
  }
  f32x4 acc[2][4];
#pragma unroll
  for (int cs = 0; cs < 2; ++cs)
#pragma unroll
    for (int nt = 0; nt < 4; ++nt) acc[cs][nt] = f32x4{0.f, 0.f, 0.f, 0.f};
  __syncthreads();

  for (int ch = 0; ch < 8; ++ch) {
    const int mg0 = ch * 64 + w * 16;  // wave's 16 logit rows
    // ---- logits U (3-split MFMA) ----
    f32x4 U[4];
#pragma unroll
    for (int nt = 0; nt < 4; ++nt) U[nt] = f32x4{0.f, 0.f, 0.f, 0.f};
#pragma unroll
    for (int k = 0; k < 4; ++k) {
      const size_t ra = (size_t)(mg0 + l15) * C_ + k * 32 + q * 8;
      bf16x8 ah = *(const bf16x8*)&Wuh[ra];
      bf16x8 al = *(const bf16x8*)&Wul[ra];
#pragma unroll
      for (int nt = 0; nt < 4; ++nt) {
        const int o = (nt * 16 + l15) * 136 + k * 32 + q * 8;
        bf16x8 bh = *(bf16x8*)&XH[o];
        bf16x8 bl = *(bf16x8*)&XL[o];
        U[nt] = MFMA16(ah, bh, U[nt]);
        U[nt] = MFMA16(ah, bl, U[nt]);
        U[nt] = MFMA16(al, bh, U[nt]);
      }
    }
    // bias (per m-row)
    float bi[4];
#pragma unroll
    for (int r = 0; r < 4; ++r) bi[r] = bun[mg0 + q * 4 + r];
#pragma unroll
    for (int nt = 0; nt < 4; ++nt)
#pragma unroll
      for (int r = 0; r < 4; ++r) U[nt][r] += bi[r];

    // ---- wave-local column max ----
#pragma unroll
    for (int nt = 0; nt < 4; ++nt) {
      float m4 = fmaxf(fmaxf(U[nt][0], U[nt][1]), fmaxf(U[nt][2], U[nt][3]));
      m4 = fmaxf(m4, __shfl_xor(m4, 16));
      m4 = fmaxf(m4, __shfl_xor(m4, 32));
      if (lane < 16) colmax_s[w][nt * 16 + lane] = m4;
    }
    __syncthreads();
    if (t < 64) {
      float Mo = M_s[t];
      float Mn = fmaxf(fmaxf(colmax_s[0][t], colmax_s[1][t]),
                       fmaxf(colmax_s[2][t], colmax_s[3][t]));
      Mn = fmaxf(Mo, Mn);
      alpha_s[t] = __expf(Mo - Mn);
      M_s[t] = Mn;
    }
    __syncthreads();
    // ---- P = exp(U-M), colsum, stage P^T hi/lo, rescale acc ----
#pragma unroll
    for (int nt = 0; nt < 4; ++nt) {
      const float Mn = M_s[nt * 16 + l15];
      bf16x4 ph4, pl4;
      float s = 0.f;
#pragma unroll
      for (int r = 0; r < 4; ++r) {
        float p = __expf(U[nt][r] - Mn);
        s += p;
        bf16_t hh = (bf16_t)p;
        ph4[r] = hh;
        pl4[r] = (bf16_t)(p - (float)hh);
      }
      s += __shfl_xor(s, 16);
      s += __shfl_xor(s, 32);
      if (lane < 16) colsum_s[w][nt * 16 + lane] = s;
      const int o = (nt * 16 + l15) * 72 + w * 16 + q * 4;
      *(bf16x4*)&PH[o] = ph4;
      *(bf16x4*)&PL[o] = pl4;
      const float al = alpha_s[nt * 16 + l15];
      acc[0][nt] *= al;
      acc[1][nt] *= al;
    }
    __syncthreads();
    if (t < 64)
      L_s[t] = L_s[t] * alpha_s[t] +
               colsum_s[0][t] + colsum_s[1][t] + colsum_s[2][t] + colsum_s[3][t];
    // ---- apply: out += x1 · P^T (3-split MFMA) ----
#pragma unroll
    for (int ks = 0; ks < 2; ++ks) {
      bf16x8 ah2[2], al2[2];
#pragma unroll
      for (int cs = 0; cs < 2; ++cs) {
        const size_t ga =
            ((size_t)b * 128 + w * 32 + cs * 16 + l15) * M_ + ch * 64 + ks * 32 + q * 8;
        ah2[cs] = *(const bf16x8*)&x1hi[ga];
        al2[cs] = *(const bf16x8*)&x1lo[ga];
      }
#pragma unroll
      for (int nt = 0; nt < 4; ++nt) {
        const int o = (nt * 16 + l15) * 72 + ks * 32 + q * 8;
        bf16x8 bh = *(bf16x8*)&PH[o];
        bf16x8 bl = *(bf16x8*)&PL[o];
#pragma unroll
        for (int cs = 0; cs < 2; ++cs) {
          acc[cs][nt] = MFMA16(ah2[cs], bh, acc[cs][nt]);
          acc[cs][nt] = MFMA16(ah2[cs], bl, acc[cs][nt]);
          acc[cs][nt] = MFMA16(al2[cs], bh, acc[cs][nt]);
        }
      }
    }
  }
  __syncthreads();
#pragma unroll
  for (int nt = 0; nt < 4; ++nt) {
    const float invL = 1.f / L_s[nt * 16 + l15];
#pragma unroll
    for (int cs = 0; cs < 2; ++cs) {
      const int c = w * 32 + cs * 16 + q * 4;
#pragma unroll
      for (int r = 0; r < 4; ++r)
        out[((size_t)b * 128 + c + r) * (size_t)N_ + n0 + nt * 16 + l15] =
            acc[cs][nt][r] * invL;
    }
  }
}

// ---------------------------------------------------------------------------
extern "C" void kernel_launch(void* const* d_in, const int* in_sizes, int n_in,
                              void* d_out, int out_size, void* d_ws, size_t ws_size,
                              hipStream_t stream) {
  const float* x = (const float*)d_in[0];
  const float* W_pool = (const float*)d_in[1];
  const float* Wf = (const float*)d_in[2];
  const float* gamma = (const float*)d_in[3];
  const float* beta = (const float*)d_in[4];
  const float* W_unpool = (const float*)d_in[5];
  const float* b_unpool = (const float*)d_in[6];
  float* out = (float*)d_out;

  char* ws = (char*)d_ws;
  float* h_part = (float*)ws; ws += (size_t)4 * 32 * 512 * 128 * 4;  // 33.55 MB
  float* ml = (float*)ws;     ws += (size_t)4 * 32 * 512 * 2 * 4;    // 0.52 MB
  float* hbuf = (float*)ws;   ws += (size_t)512 * 4096 * 4;          // 8.39 MB
  float* stats = (float*)ws;  ws += NL * 1024 * 4;
  bf16_t* xsThi = (bf16_t*)ws; ws += (size_t)32 * N_ * C_ * 2;       // 33.55 MB
  bf16_t* xsTlo = (bf16_t*)ws; ws += (size_t)32 * N_ * C_ * 2;       // 33.55 MB
  bf16_t* Wuh = (bf16_t*)ws;  ws += (size_t)M_ * C_ * 2;             // 0.13 MB
  bf16_t* Wul = (bf16_t*)ws;  ws += (size_t)M_ * C_ * 2;             // 0.13 MB
  // aliased into h_part (dead after k_combine):
  char* hp = (char*)h_part;
  float* ybuf = (float*)(hp);                  // 8.39 MB
  bf16_t* Whi = (bf16_t*)(hp + 8388608);       // 3.15 MB
  bf16_t* Wlo = (bf16_t*)(hp + 11534336);      // 3.15 MB
  bf16_t* hThi = (bf16_t*)(hp + 14680064);     // 4.19 MB
  bf16_t* hTlo = (bf16_t*)(hp + 18874368);     // 4.19 MB

  hipMemsetAsync(stats, 0, NL * 1024 * 4, stream);
  k_xsplit<<<dim3(64, 32), 256, 0, stream>>>(x, xsThi, xsTlo);
  k_wsplit<<<dim3(64), 256, 0, stream>>>(W_unpool, Wuh, Wul);
  k_pool<<<dim3(16, 32), 256, 0, stream>>>(x, W_pool, h_part, ml);
  k_combine<<<dim3(16384), 128, 0, stream>>>(h_part, ml, hbuf);
  k_wsplit<<<dim3(1536), 256, 0, stream>>>(Wf, Whi, Wlo);
  k_hsplit<<<dim3(8, 64), 256, 0, stream>>>(hbuf, hThi, hTlo);
  for (int l = 0; l < NL; ++l) {
    k_layerA<<<dim3(16, 32), 256, 0, stream>>>(Whi, Wlo, hThi, hTlo, l, ybuf, stats);
    k_layerB<<<dim3(2048), 256, 0, stream>>>(ybuf, hbuf, stats, gamma, beta, l);
    k_hsplit<<<dim3(8, 64), 256, 0, stream>>>(hbuf, hThi, hTlo);
  }
  k_unpool<<<dim3(64, 32), 256, 0, stream>>>(xsThi, xsTlo, Wuh, Wul, b_unpool,
                                             hThi, hTlo, out);
}

// Round 5
// 963.691 us; speedup vs baseline: 2.3772x; 1.1365x over previous
//
#include <hip/hip_runtime.h>
#include <hip/hip_bf16.h>

typedef float f32x4 __attribute__((ext_vector_type(4)));
typedef __bf16 bf16_t;
typedef __bf16 bf16x4 __attribute__((ext_vector_type(4)));
typedef __bf16 bf16x8 __attribute__((ext_vector_type(8)));

#define MFMA16(a, b, c) __builtin_amdgcn_mfma_f32_16x16x32_bf16(a, b, c, 0, 0, 0)

constexpr int C_ = 128;
constexpr int N_ = 4096;
constexpr int M_ = 512;
constexpr int NL = 6;

#define NEG_INF (-__builtin_huge_valf())

// ---------------------------------------------------------------------------
// Split fp32 array -> hi/lo bf16 (same layout). 1024 elems per block.
// ---------------------------------------------------------------------------
__global__ __launch_bounds__(256) void k_wsplit(const float* __restrict__ W,
                                                bf16_t* __restrict__ hi,
                                                bf16_t* __restrict__ lo) {
  const size_t i4 = ((size_t)blockIdx.x * 256 + threadIdx.x) * 4;
  f32x4 v = *(const f32x4*)&W[i4];
  bf16x4 h4, l4;
#pragma unroll
  for (int k = 0; k < 4; ++k) {
    bf16_t h = (bf16_t)v[k];
    h4[k] = h;
    l4[k] = (bf16_t)(v[k] - (float)h);
  }
  *(bf16x4*)&hi[i4] = h4;
  *(bf16x4*)&lo[i4] = l4;
}

// ---------------------------------------------------------------------------
// xs [b][c][n] fp32 -> xsThi/xsTlo [b][n][c] bf16 (transpose + split).
// ---------------------------------------------------------------------------
__global__ __launch_bounds__(256) void k_xsplit(const float* __restrict__ xs,
                                                bf16_t* __restrict__ thi,
                                                bf16_t* __restrict__ tlo) {
  __shared__ float T[128 * 68];  // [c][n]
  const int n0 = blockIdx.x * 64, b = blockIdx.y;
  const int t = threadIdx.x;
  const float* xsb = xs + (size_t)b * C_ * N_;
#pragma unroll
  for (int i = 0; i < 8; ++i) {
    int slot = i * 256 + t;  // 0..2047
    int c = slot >> 4, n4 = (slot & 15) * 4;
    *(f32x4*)&T[c * 68 + n4] = *(const f32x4*)&xsb[(size_t)c * N_ + n0 + n4];
  }
  __syncthreads();
  const int n = t >> 2, cb = (t & 3) * 32;
  bf16x8 h8[4], l8[4];
#pragma unroll
  for (int g = 0; g < 4; ++g)
#pragma unroll
    for (int j = 0; j < 8; ++j) {
      float v = T[(cb + g * 8 + j) * 68 + n];
      bf16_t hh = (bf16_t)v;
      h8[g][j] = hh;
      l8[g][j] = (bf16_t)(v - (float)hh);
    }
  const size_t base = ((size_t)b * N_ + n0 + n) * C_ + cb;
#pragma unroll
  for (int g = 0; g < 4; ++g) {
    *(bf16x8*)&thi[base + g * 8] = h8[g];
    *(bf16x8*)&tlo[base + g * 8] = l8[g];
  }
}

// ---------------------------------------------------------------------------
// Pool v2 (MFMA flash over n, row softmax).
// grid (8 mt x 2 seg, 32 b), 4 waves; wave w owns m rows m0+w*16..+16.
// Logits: U[16m][64n] = Wp·xsT^T (split, LDS B-frags).  In-wave online
// softmax.  Apply: h[16m][128c] += P·xs^T (split, P from per-wave LDS,
// B-frags from xshi/xslo [b][c][n] global).
// ---------------------------------------------------------------------------
__global__ __launch_bounds__(256) void k_pool(const bf16_t* __restrict__ xsThi,
                                              const bf16_t* __restrict__ xsTlo,
                                              const bf16_t* __restrict__ xshi,
                                              const bf16_t* __restrict__ xslo,
                                              const bf16_t* __restrict__ Wph,
                                              const bf16_t* __restrict__ Wpl,
                                              float* __restrict__ h_part,
                                              float* __restrict__ ml) {
  __shared__ bf16_t XH[64 * 136], XL[64 * 136];   // xsT tile [n][c]
  __shared__ bf16_t PWH[4][16 * 68], PWL[4][16 * 68];  // per-wave P [m][n]
  const int bx = blockIdx.x, b = blockIdx.y;
  const int mt = bx >> 1, seg = bx & 1;
  const int m0 = mt * 64;
  const int t = threadIdx.x, w = t >> 6, lane = t & 63, l15 = lane & 15, q = lane >> 4;

  // preload Wp A-frags (hi/lo), K=C=128 -> 4 k-steps
  bf16x8 aWh[4], aWl[4];
#pragma unroll
  for (int k = 0; k < 4; ++k) {
    const size_t ra = (size_t)(m0 + w * 16 + l15) * C_ + k * 32 + q * 8;
    aWh[k] = *(const bf16x8*)&Wph[ra];
    aWl[k] = *(const bf16x8*)&Wpl[ra];
  }

  f32x4 acc[8];
#pragma unroll
  for (int cs = 0; cs < 8; ++cs) acc[cs] = f32x4{0.f, 0.f, 0.f, 0.f};
  float mrun[4], lrun[4];
#pragma unroll
  for (int r = 0; r < 4; ++r) { mrun[r] = NEG_INF; lrun[r] = 0.f; }

  for (int ch = 0; ch < 32; ++ch) {
    const int n0g = seg * 2048 + ch * 64;
    __syncthreads();
    // stage xsT tile
#pragma unroll
    for (int i = 0; i < 4; ++i) {
      int slot = i * 256 + t;
      int n = slot >> 4, cg = (slot & 15) * 8;
      const size_t g = ((size_t)b * N_ + n0g + n) * C_ + cg;
      *(bf16x8*)&XH[n * 136 + cg] = *(const bf16x8*)&xsThi[g];
      *(bf16x8*)&XL[n * 136 + cg] = *(const bf16x8*)&xsTlo[g];
    }
    __syncthreads();

    // ---- logits U[16m][64n] ----
    f32x4 U[4];
#pragma unroll
    for (int nt = 0; nt < 4; ++nt) U[nt] = f32x4{0.f, 0.f, 0.f, 0.f};
#pragma unroll
    for (int k = 0; k < 4; ++k) {
#pragma unroll
      for (int nt = 0; nt < 4; ++nt) {
        const int o = (nt * 16 + l15) * 136 + k * 32 + q * 8;
        bf16x8 bh = *(bf16x8*)&XH[o];
        bf16x8 bl = *(bf16x8*)&XL[o];
        U[nt] = MFMA16(aWh[k], bh, U[nt]);
        U[nt] = MFMA16(aWh[k], bl, U[nt]);
        U[nt] = MFMA16(aWl[k], bh, U[nt]);
      }
    }

    // ---- in-wave online row softmax (row = q*4+r) ----
    float alpha[4];
#pragma unroll
    for (int r = 0; r < 4; ++r) {
      float mx = fmaxf(fmaxf(U[0][r], U[1][r]), fmaxf(U[2][r], U[3][r]));
#pragma unroll
      for (int off = 1; off < 16; off <<= 1) mx = fmaxf(mx, __shfl_xor(mx, off));
      float mn = fmaxf(mrun[r], mx);
      alpha[r] = __expf(mrun[r] - mn);
      mrun[r] = mn;
    }
    float ssum[4] = {0.f, 0.f, 0.f, 0.f};
#pragma unroll
    for (int nt = 0; nt < 4; ++nt) {
#pragma unroll
      for (int r = 0; r < 4; ++r) {
        float p = __expf(U[nt][r] - mrun[r]);
        ssum[r] += p;
        bf16_t ph = (bf16_t)p;
        PWH[w][(q * 4 + r) * 68 + nt * 16 + l15] = ph;
        PWL[w][(q * 4 + r) * 68 + nt * 16 + l15] = (bf16_t)(p - (float)ph);
      }
    }
#pragma unroll
    for (int r = 0; r < 4; ++r) {
      float s = ssum[r];
#pragma unroll
      for (int off = 1; off < 16; off <<= 1) s += __shfl_xor(s, off);
      lrun[r] = lrun[r] * alpha[r] + s;
    }
    // rescale acc
#pragma unroll
    for (int cs = 0; cs < 8; ++cs)
#pragma unroll
      for (int r = 0; r < 4; ++r) acc[cs][r] *= alpha[r];

    // ---- apply: h += P · xs^T  (per-wave P, global B-frags) ----
#pragma unroll
    for (int ks = 0; ks < 2; ++ks) {
      bf16x8 aPh = *(bf16x8*)&PWH[w][l15 * 68 + ks * 32 + q * 8];
      bf16x8 aPl = *(bf16x8*)&PWL[w][l15 * 68 + ks * 32 + q * 8];
#pragma unroll
      for (int cs = 0; cs < 8; ++cs) {
        const size_t gb = ((size_t)b * C_ + cs * 16 + l15) * N_ + n0g + ks * 32 + q * 8;
        bf16x8 bh = *(const bf16x8*)&xshi[gb];
        bf16x8 bl = *(const bf16x8*)&xslo[gb];
        acc[cs] = MFMA16(aPh, bh, acc[cs]);
        acc[cs] = MFMA16(aPh, bl, acc[cs]);
        acc[cs] = MFMA16(aPl, bh, acc[cs]);
      }
    }
  }

  // epilogue: unnormalized partials + (M,L)
  const size_t sb = (size_t)seg * 32 + b;
  if (l15 == 0) {
#pragma unroll
    for (int r = 0; r < 4; ++r) {
      const int m = m0 + w * 16 + q * 4 + r;
      ml[(sb * 512 + m) * 2] = mrun[r];
      ml[(sb * 512 + m) * 2 + 1] = lrun[r];
    }
  }
#pragma unroll
  for (int cs = 0; cs < 8; ++cs)
#pragma unroll
    for (int r = 0; r < 4; ++r) {
      const int m = m0 + w * 16 + q * 4 + r;
      h_part[(sb * 512 + m) * 128 + cs * 16 + l15] = acc[cs][r];
    }
}

// ---------------------------------------------------------------------------
// Combine 2 n-segments: h[m][b*128+c].
// ---------------------------------------------------------------------------
__global__ __launch_bounds__(128) void k_combine(const float* __restrict__ h_part,
                                                 const float* __restrict__ ml,
                                                 float* __restrict__ hbuf) {
  const int mb = blockIdx.x;
  const int m = mb >> 5, b = mb & 31;
  const int c = threadIdx.x;
  float Ms[2], M = NEG_INF;
#pragma unroll
  for (int s = 0; s < 2; ++s) {
    Ms[s] = ml[(((size_t)s * 32 + b) * 512 + m) * 2];
    M = fmaxf(M, Ms[s]);
  }
  float w[2], L = 0.f;
#pragma unroll
  for (int s = 0; s < 2; ++s) {
    w[s] = __expf(Ms[s] - M);
    L += w[s] * ml[(((size_t)s * 32 + b) * 512 + m) * 2 + 1];
  }
  float acc = 0.f;
#pragma unroll
  for (int s = 0; s < 2; ++s)
    acc += w[s] * h_part[(((size_t)s * 32 + b) * 512 + m) * 128 + c];
  hbuf[(size_t)m * 4096 + b * 128 + c] = acc / L;
}

// ---------------------------------------------------------------------------
// h [512m][4096bc] fp32 -> hT hi/lo bf16 [4096bc][512m].  64x64 tiles.
// ---------------------------------------------------------------------------
__global__ __launch_bounds__(256) void k_hsplit(const float* __restrict__ h,
                                                bf16_t* __restrict__ thi,
                                                bf16_t* __restrict__ tlo) {
  __shared__ float T[64 * 65];  // [c][m]
  const int m0 = blockIdx.x * 64, c0 = blockIdx.y * 64;
  const int t = threadIdx.x;
#pragma unroll
  for (int ii = 0; ii < 4; ++ii) {
    int slot = ii * 256 + t;
    int m = slot >> 4, c4 = (slot & 15) * 4;
    f32x4 v = *(const f32x4*)&h[(size_t)(m0 + m) * 4096 + c0 + c4];
#pragma unroll
    for (int k = 0; k < 4; ++k) T[(c4 + k) * 65 + m] = v[k];
  }
  __syncthreads();
  const int row = t >> 2, mg = (t & 3) * 16;
  bf16x8 h8[2], l8[2];
#pragma unroll
  for (int half = 0; half < 2; ++half)
#pragma unroll
    for (int j = 0; j < 8; ++j) {
      float v = T[row * 65 + mg + half * 8 + j];
      bf16_t hh = (bf16_t)v;
      h8[half][j] = hh;
      l8[half][j] = (bf16_t)(v - (float)hh);
    }
  bf16_t* ph = &thi[(size_t)(c0 + row) * 512 + m0 + mg];
  bf16_t* pl = &tlo[(size_t)(c0 + row) * 512 + m0 + mg];
  *(bf16x8*)ph = h8[0];
  *(bf16x8*)(ph + 8) = h8[1];
  *(bf16x8*)pl = l8[0];
  *(bf16x8*)(pl + 8) = l8[1];
}

// ---------------------------------------------------------------------------
// Layer GEMM via split-bf16 MFMA — unchanged.
// ---------------------------------------------------------------------------
__global__ __launch_bounds__(256) void k_layerA(const bf16_t* __restrict__ Whi,
                                                const bf16_t* __restrict__ Wlo,
                                                const bf16_t* __restrict__ hThi,
                                                const bf16_t* __restrict__ hTlo,
                                                int l, float* __restrict__ ybuf,
                                                float* __restrict__ stats) {
  const int o0 = blockIdx.x * 32;
  const int bc0 = blockIdx.y * 128;
  const int t = threadIdx.x;
  const int w = t >> 6, lane = t & 63, l15 = lane & 15, q = lane >> 4;
  const int bcw = bc0 + w * 32;
  const bf16_t* Wh = Whi + (size_t)l * M_ * M_;
  const bf16_t* Wl = Wlo + (size_t)l * M_ * M_;

  f32x4 acc[2][2];
#pragma unroll
  for (int i = 0; i < 2; ++i)
#pragma unroll
    for (int j = 0; j < 2; ++j) acc[i][j] = f32x4{0.f, 0.f, 0.f, 0.f};

  for (int k0 = 0; k0 < M_; k0 += 32) {
    bf16x8 ah[2], al[2], bh[2], bl[2];
#pragma unroll
    for (int os = 0; os < 2; ++os) {
      const size_t ro = (size_t)(o0 + os * 16 + l15) * M_ + k0 + q * 8;
      ah[os] = *(const bf16x8*)&Wh[ro];
      al[os] = *(const bf16x8*)&Wl[ro];
    }
#pragma unroll
    for (int ns = 0; ns < 2; ++ns) {
      const size_t rb = (size_t)(bcw + ns * 16 + l15) * M_ + k0 + q * 8;
      bh[ns] = *(const bf16x8*)&hThi[rb];
      bl[ns] = *(const bf16x8*)&hTlo[rb];
    }
#pragma unroll
    for (int os = 0; os < 2; ++os)
#pragma unroll
      for (int ns = 0; ns < 2; ++ns) {
        acc[os][ns] = MFMA16(ah[os], bh[ns], acc[os][ns]);
        acc[os][ns] = MFMA16(ah[os], bl[ns], acc[os][ns]);
        acc[os][ns] = MFMA16(al[os], bh[ns], acc[os][ns]);
      }
  }

  float s1[2][4], s2[2][4];
#pragma unroll
  for (int os = 0; os < 2; ++os)
#pragma unroll
    for (int r = 0; r < 4; ++r) {
      float a = 0.f, b2 = 0.f;
#pragma unroll
      for (int ns = 0; ns < 2; ++ns) {
        float v = acc[os][ns][r];
        ybuf[(size_t)(o0 + os * 16 + q * 4 + r) * 4096 + bcw + ns * 16 + l15] = v;
        a += v;
        b2 += v * v;
      }
      s1[os][r] = a;
      s2[os][r] = b2;
    }
#pragma unroll
  for (int os = 0; os < 2; ++os)
#pragma unroll
    for (int r = 0; r < 4; ++r) {
#pragma unroll
      for (int off = 1; off < 16; off <<= 1) {
        s1[os][r] += __shfl_xor(s1[os][r], off);
        s2[os][r] += __shfl_xor(s2[os][r], off);
      }
      if (l15 == 0) {
        const int o = o0 + os * 16 + q * 4 + r;
        atomicAdd(&stats[l * 1024 + o], s1[os][r]);
        atomicAdd(&stats[l * 1024 + 512 + o], s2[os][r]);
      }
    }
}

// ---------------------------------------------------------------------------
// BN + residual + relu elementwise — unchanged.
// ---------------------------------------------------------------------------
__global__ __launch_bounds__(256) void k_layerB(const float* __restrict__ ybuf,
                                                float* __restrict__ hbuf,
                                                const float* __restrict__ stats,
                                                const float* __restrict__ gamma,
                                                const float* __restrict__ beta, int l) {
  const size_t i4 = ((size_t)blockIdx.x * 256 + threadIdx.x) * 4;
  const int o = (int)(i4 >> 12);
  f32x4 y = *(const f32x4*)&ybuf[i4];
  f32x4 h = *(const f32x4*)&hbuf[i4];
  const float mu = stats[l * 1024 + o] * (1.f / 4096.f);
  const float var = stats[l * 1024 + 512 + o] * (1.f / 4096.f) - mu * mu;
  const float rs = rsqrtf(var + 1e-5f);
  const float g = gamma[l * 512 + o];
  const float bt = beta[l * 512 + o];
  f32x4 r;
#pragma unroll
  for (int jj = 0; jj < 4; ++jj)
    r[jj] = fmaxf((y[jj] - mu) * rs * g + bt + h[jj], 0.f);
  *(f32x4*)&hbuf[i4] = r;
}

// ---------------------------------------------------------------------------
// Unpool v3 (MFMA flash over m) — unchanged.
// ---------------------------------------------------------------------------
__global__ __launch_bounds__(256) void k_unpool(const bf16_t* __restrict__ xsThi,
                                                const bf16_t* __restrict__ xsTlo,
                                                const bf16_t* __restrict__ Wuh,
                                                const bf16_t* __restrict__ Wul,
                                                const float* __restrict__ bun,
                                                const bf16_t* __restrict__ x1hi,
                                                const bf16_t* __restrict__ x1lo,
                                                float* __restrict__ out) {
  __shared__ bf16_t XH[64 * 136], XL[64 * 136];
  __shared__ bf16_t PH[64 * 72], PL[64 * 72];
  __shared__ float colmax_s[4][64], colsum_s[4][64];
  __shared__ float M_s[64], L_s[64], alpha_s[64];
  const int n0 = blockIdx.x * 64, b = blockIdx.y;
  const int t = threadIdx.x, w = t >> 6, lane = t & 63, l15 = lane & 15, q = lane >> 4;

#pragma unroll
  for (int i = 0; i < 4; ++i) {
    int slot = i * 256 + t;
    int n = slot >> 4, cg = (slot & 15) * 8;
    const size_t g = ((size_t)b * N_ + n0 + n) * C_ + cg;
    *(bf16x8*)&XH[n * 136 + cg] = *(const bf16x8*)&xsThi[g];
    *(bf16x8*)&XL[n * 136 + cg] = *(const bf16x8*)&xsTlo[g];
  }
  if (t < 64) {
    M_s[t] = NEG_INF;
    L_s[t] = 0.f;
  }
  f32x4 acc[2][4];
#pragma unroll
  for (int cs = 0; cs < 2; ++cs)
#pragma unroll
    for (int nt = 0; nt < 4; ++nt) acc[cs][nt] = f32x4{0.f, 0.f, 0.f, 0.f};
  __syncthreads();

  for (int ch = 0; ch < 8; ++ch) {
    const int mg0 = ch * 64 + w * 16;
    f32x4 U[4];
#pragma unroll
    for (int nt = 0; nt < 4; ++nt) U[nt] = f32x4{0.f, 0.f, 0.f, 0.f};
#pragma unroll
    for (int k = 0; k < 4; ++k) {
      const size_t ra = (size_t)(mg0 + l15) * C_ + k * 32 + q * 8;
      bf16x8 ah = *(const bf16x8*)&Wuh[ra];
      bf16x8 al = *(const bf16x8*)&Wul[ra];
#pragma unroll
      for (int nt = 0; nt < 4; ++nt) {
        const int o = (nt * 16 + l15) * 136 + k * 32 + q * 8;
        bf16x8 bh = *(bf16x8*)&XH[o];
        bf16x8 bl = *(bf16x8*)&XL[o];
        U[nt] = MFMA16(ah, bh, U[nt]);
        U[nt] = MFMA16(ah, bl, U[nt]);
        U[nt] = MFMA16(al, bh, U[nt]);
      }
    }
    float bi[4];
#pragma unroll
    for (int r = 0; r < 4; ++r) bi[r] = bun[mg0 + q * 4 + r];
#pragma unroll
    for (int nt = 0; nt < 4; ++nt)
#pragma unroll
      for (int r = 0; r < 4; ++r) U[nt][r] += bi[r];

#pragma unroll
    for (int nt = 0; nt < 4; ++nt) {
      float m4 = fmaxf(fmaxf(U[nt][0], U[nt][1]), fmaxf(U[nt][2], U[nt][3]));
      m4 = fmaxf(m4, __shfl_xor(m4, 16));
      m4 = fmaxf(m4, __shfl_xor(m4, 32));
      if (lane < 16) colmax_s[w][nt * 16 + lane] = m4;
    }
    __syncthreads();
    if (t < 64) {
      float Mo = M_s[t];
      float Mn = fmaxf(fmaxf(colmax_s[0][t], colmax_s[1][t]),
                       fmaxf(colmax_s[2][t], colmax_s[3][t]));
      Mn = fmaxf(Mo, Mn);
      alpha_s[t] = __expf(Mo - Mn);
      M_s[t] = Mn;
    }
    __syncthreads();
#pragma unroll
    for (int nt = 0; nt < 4; ++nt) {
      const float Mn = M_s[nt * 16 + l15];
      bf16x4 ph4, pl4;
      float s = 0.f;
#pragma unroll
      for (int r = 0; r < 4; ++r) {
        float p = __expf(U[nt][r] - Mn);
        s += p;
        bf16_t hh = (bf16_t)p;
        ph4[r] = hh;
        pl4[r] = (bf16_t)(p - (float)hh);
      }
      s += __shfl_xor(s, 16);
      s += __shfl_xor(s, 32);
      if (lane < 16) colsum_s[w][nt * 16 + lane] = s;
      const int o = (nt * 16 + l15) * 72 + w * 16 + q * 4;
      *(bf16x4*)&PH[o] = ph4;
      *(bf16x4*)&PL[o] = pl4;
      const float al = alpha_s[nt * 16 + l15];
      acc[0][nt] *= al;
      acc[1][nt] *= al;
    }
    __syncthreads();
    if (t < 64)
      L_s[t] = L_s[t] * alpha_s[t] +
               colsum_s[0][t] + colsum_s[1][t] + colsum_s[2][t] + colsum_s[3][t];
#pragma unroll
    for (int ks = 0; ks < 2; ++ks) {
      bf16x8 ah2[2], al2[2];
#pragma unroll
      for (int cs = 0; cs < 2; ++cs) {
        const size_t ga =
            ((size_t)b * 128 + w * 32 + cs * 16 + l15) * M_ + ch * 64 + ks * 32 + q * 8;
        ah2[cs] = *(const bf16x8*)&x1hi[ga];
        al2[cs] = *(const bf16x8*)&x1lo[ga];
      }
#pragma unroll
      for (int nt = 0; nt < 4; ++nt) {
        const int o = (nt * 16 + l15) * 72 + ks * 32 + q * 8;
        bf16x8 bh = *(bf16x8*)&PH[o];
        bf16x8 bl = *(bf16x8*)&PL[o];
#pragma unroll
        for (int cs = 0; cs < 2; ++cs) {
          acc[cs][nt] = MFMA16(ah2[cs], bh, acc[cs][nt]);
          acc[cs][nt] = MFMA16(ah2[cs], bl, acc[cs][nt]);
          acc[cs][nt] = MFMA16(al2[cs], bh, acc[cs][nt]);
        }
      }
    }
  }
  __syncthreads();
#pragma unroll
  for (int nt = 0; nt < 4; ++nt) {
    const float invL = 1.f / L_s[nt * 16 + l15];
#pragma unroll
    for (int cs = 0; cs < 2; ++cs) {
      const int c = w * 32 + cs * 16 + q * 4;
#pragma unroll
      for (int r = 0; r < 4; ++r)
        out[((size_t)b * 128 + c + r) * (size_t)N_ + n0 + nt * 16 + l15] =
            acc[cs][nt][r] * invL;
    }
  }
}

// ---------------------------------------------------------------------------
extern "C" void kernel_launch(void* const* d_in, const int* in_sizes, int n_in,
                              void* d_out, int out_size, void* d_ws, size_t ws_size,
                              hipStream_t stream) {
  const float* x = (const float*)d_in[0];
  const float* W_pool = (const float*)d_in[1];
  const float* Wf = (const float*)d_in[2];
  const float* gamma = (const float*)d_in[3];
  const float* beta = (const float*)d_in[4];
  const float* W_unpool = (const float*)d_in[5];
  const float* b_unpool = (const float*)d_in[6];
  float* out = (float*)d_out;

  char* ws = (char*)d_ws;
  float* h_part = (float*)ws; ws += (size_t)2 * 32 * 512 * 128 * 4;  // 16.78 MB
  float* ml = (float*)ws;     ws += (size_t)2 * 32 * 512 * 2 * 4;    // 0.52 MB
  float* hbuf = (float*)ws;   ws += (size_t)512 * 4096 * 4;          // 8.39 MB
  float* stats = (float*)ws;  ws += NL * 1024 * 4;
  bf16_t* xsThi = (bf16_t*)ws; ws += (size_t)32 * N_ * C_ * 2;       // 33.55 MB
  bf16_t* xsTlo = (bf16_t*)ws; ws += (size_t)32 * N_ * C_ * 2;       // 33.55 MB
  bf16_t* xshi = (bf16_t*)ws;  ws += (size_t)32 * N_ * C_ * 2;       // 33.55 MB
  bf16_t* xslo = (bf16_t*)ws;  ws += (size_t)32 * N_ * C_ * 2;       // 33.55 MB
  bf16_t* Wuh = (bf16_t*)ws;  ws += (size_t)M_ * C_ * 2;
  bf16_t* Wul = (bf16_t*)ws;  ws += (size_t)M_ * C_ * 2;
  bf16_t* Wph = (bf16_t*)ws;  ws += (size_t)M_ * C_ * 2;
  bf16_t* Wpl = (bf16_t*)ws;  ws += (size_t)M_ * C_ * 2;
  bf16_t* Whi = (bf16_t*)ws;  ws += (size_t)NL * M_ * M_ * 2;        // 3.15 MB
  bf16_t* Wlo = (bf16_t*)ws;  ws += (size_t)NL * M_ * M_ * 2;        // 3.15 MB
  // aliased into h_part (dead after k_combine):
  char* hp = (char*)h_part;
  float* ybuf = (float*)(hp);                  // 8.39 MB
  bf16_t* hThi = (bf16_t*)(hp + 8388608);      // 4.19 MB
  bf16_t* hTlo = (bf16_t*)(hp + 12582912);     // 4.19 MB

  hipMemsetAsync(stats, 0, NL * 1024 * 4, stream);
  k_xsplit<<<dim3(64, 32), 256, 0, stream>>>(x, xsThi, xsTlo);
  k_wsplit<<<dim3(16384), 256, 0, stream>>>(x, xshi, xslo);
  k_wsplit<<<dim3(64), 256, 0, stream>>>(W_pool, Wph, Wpl);
  k_wsplit<<<dim3(64), 256, 0, stream>>>(W_unpool, Wuh, Wul);
  k_wsplit<<<dim3(1536), 256, 0, stream>>>(Wf, Whi, Wlo);
  k_pool<<<dim3(16, 32), 256, 0, stream>>>(xsThi, xsTlo, xshi, xslo, Wph, Wpl,
                                           h_part, ml);
  k_combine<<<dim3(16384), 128, 0, stream>>>(h_part, ml, hbuf);
  k_hsplit<<<dim3(8, 64), 256, 0, stream>>>(hbuf, hThi, hTlo);
  for (int l = 0; l < NL; ++l) {
    k_layerA<<<dim3(16, 32), 256, 0, stream>>>(Whi, Wlo, hThi, hTlo, l, ybuf, stats);
    k_layerB<<<dim3(2048), 256, 0, stream>>>(ybuf, hbuf, stats, gamma, beta, l);
    k_hsplit<<<dim3(8, 64), 256, 0, stream>>>(hbuf, hThi, hTlo);
  }
  k_unpool<<<dim3(64, 32), 256, 0, stream>>>(xsThi, xsTlo, Wuh, Wul, b_unpool,
                                             hThi, hTlo, out);
}